// Round 2
// baseline (1983.269 us; speedup 1.0000x reference)
//
#include <hip/hip_runtime.h>
#include <math.h>

// ---------------- complex helpers (float2 = re,im) ----------------
typedef float2 cf;

__device__ __forceinline__ cf mkc(float x, float y){ return make_float2(x,y); }
__device__ __forceinline__ cf lo4(float4 v){ return mkc(v.x, v.y); }
__device__ __forceinline__ cf hi4(float4 v){ return mkc(v.z, v.w); }

// acc += a*b
__device__ __forceinline__ void cmad(cf& acc, cf a, cf b){
    acc.x = fmaf(a.x, b.x, fmaf(-a.y, b.y, acc.x));
    acc.y = fmaf(a.x, b.y, fmaf( a.y, b.x, acc.y));
}
// acc += conj(a)*b
__device__ __forceinline__ void cmadc(cf& acc, cf a, cf b){
    acc.x = fmaf(a.x, b.x, fmaf( a.y, b.y, acc.x));
    acc.y = fmaf(a.x, b.y, fmaf(-a.y, b.x, acc.y));
}
// acc += a*conj(b)
__device__ __forceinline__ void cmad_bc(cf& acc, cf a, cf b){
    acc.x = fmaf(a.x, b.x, fmaf( a.y, b.y, acc.x));
    acc.y = fmaf(a.y, b.x, fmaf(-a.x, b.y, acc.y));
}
// acc += conj(a)*conj(b)
__device__ __forceinline__ void cmad_cc(cf& acc, cf a, cf b){
    acc.x = fmaf(a.x, b.x, fmaf(-a.y, b.y, acc.x));
    acc.y = fmaf(-a.x, b.y, fmaf(-a.y, b.x, acc.y));
}
// principal complex sqrt (numpy branch conventions)
__device__ __forceinline__ cf csqrtf2(cf z){
    float x = z.x, y = z.y;
    float r = hypotf(x, y);
    if (r == 0.0f) return mkc(0.f, 0.f);
    if (x >= 0.0f){
        float t = sqrtf(0.5f*(r + x));
        return mkc(t, 0.5f*y/t);
    } else {
        float t = sqrtf(0.5f*(r - x));
        return mkc(0.5f*fabsf(y)/t, copysignf(t, y));
    }
}
// a / b
__device__ __forceinline__ cf cdiv(cf a, cf b){
    float inv = 1.0f/(b.x*b.x + b.y*b.y);
    return mkc((a.x*b.x + a.y*b.y)*inv, (a.y*b.x - a.x*b.y)*inv);
}

#define LN2F  0.69314718055994530942f
#define BETA_ 0.9f
#define OMB_  0.1f
#define EPS_  1e-8f
#define ETAF_ 0.01f
#define ETAW_ 0.01f

#define F_S  18   /* sF / sMF row stride (cf) */
#define FT_S 66   /* sFT row stride */
#define H_S  66   /* sH row stride */
#define U_S  18   /* sU row stride */
#define V_S  18   /* sV row stride */

// Mm = A_dot^H @ R_N_inv @ A_dot  — block-invariant, lives in global (L1/L2-resident 32KB)
__device__ cf g_Mm[4096];

__device__ __forceinline__ float readScalarF(const int* p){
    int iv = *p;
    if (iv >= 0 && iv < 1000000) return (float)iv;
    return __int_as_float(iv);
}
__device__ __forceinline__ int readScalarI(const int* p){
    int iv = *p;
    if (iv >= 0 && iv < 1000000) return iv;
    return (int)(__int_as_float(iv) + 0.5f);
}

__device__ __forceinline__ float blockReduceSum(float v, float* slot, int tid){
    #pragma unroll
    for (int o = 32; o > 0; o >>= 1) v += __shfl_down(v, o, 64);
    if ((tid & 63) == 0) slot[tid >> 6] = v;
    __syncthreads();
    return slot[0] + slot[1] + slot[2] + slot[3];
}
// two sums, one barrier
__device__ __forceinline__ float2 blockReduceSum2(float a, float b2, float* sA, float* sB, int tid){
    #pragma unroll
    for (int o = 32; o > 0; o >>= 1){ a += __shfl_down(a, o, 64); b2 += __shfl_down(b2, o, 64); }
    if ((tid & 63) == 0){ sA[tid >> 6] = a; sB[tid >> 6] = b2; }
    __syncthreads();
    return make_float2(sA[0]+sA[1]+sA[2]+sA[3], sB[0]+sB[1]+sB[2]+sB[3]);
}

// MF = Mm @ F ; Mm from GLOBAL (row stride 64 cf), F cols from sFT (row-contiguous b128).
// thread (nb=tid>>4, j=tid&15), 4 output rows. 16 lanes share each Mm address (broadcast).
__device__ __forceinline__ void computeMF_G(const cf* sFT, cf* sMF, int tid){
    int j = tid & 15, nb = tid >> 4;
    cf a0=mkc(0,0), a1=mkc(0,0), a2=mkc(0,0), a3=mkc(0,0);
    const float4* ftrow = (const float4*)(sFT + j*FT_S);
    #pragma unroll
    for (int kkb = 0; kkb < 4; kkb++){
        cf f[16];
        #pragma unroll
        for (int q = 0; q < 8; q++){
            float4 v = ftrow[kkb*8+q];
            f[2*q] = lo4(v); f[2*q+1] = hi4(v);
        }
        const float4* m0 = (const float4*)(g_Mm + (nb    )*64 + kkb*16);
        const float4* m1 = (const float4*)(g_Mm + (nb+16 )*64 + kkb*16);
        const float4* m2 = (const float4*)(g_Mm + (nb+32 )*64 + kkb*16);
        const float4* m3 = (const float4*)(g_Mm + (nb+48 )*64 + kkb*16);
        #pragma unroll
        for (int q = 0; q < 8; q++){
            float4 v0 = m0[q], v1 = m1[q], v2 = m2[q], v3 = m3[q];
            cmad(a0, lo4(v0), f[2*q]); cmad(a0, hi4(v0), f[2*q+1]);
            cmad(a1, lo4(v1), f[2*q]); cmad(a1, hi4(v1), f[2*q+1]);
            cmad(a2, lo4(v2), f[2*q]); cmad(a2, hi4(v2), f[2*q+1]);
            cmad(a3, lo4(v3), f[2*q]); cmad(a3, hi4(v3), f[2*q+1]);
        }
    }
    sMF[(nb   )*F_S+j]=a0; sMF[(nb+16)*F_S+j]=a1;
    sMF[(nb+32)*F_S+j]=a2; sMF[(nb+48)*F_S+j]=a3;
}

// u[m][j] = sum_n conj(H[m,n]) F[n,j], split-K over 256 threads (interleaved chunks)
__device__ __forceinline__ void uRefresh(const cf* sH, const cf* sFT, cf* sU, int tid){
    int h = tid & 1, j = (tid >> 1) & 15, m = tid >> 5;
    const float4* hp = (const float4*)(sH  + m*H_S);
    const float4* fp = (const float4*)(sFT + j*FT_S);
    cf acc = mkc(0,0);
    #pragma unroll
    for (int q = 0; q < 16; q++){
        int c = 2*q + h;
        float4 hv = hp[c], fv = fp[c];
        cmadc(acc, lo4(hv), lo4(fv));
        cmadc(acc, hi4(hv), hi4(fv));
    }
    acc.x += __shfl_xor(acc.x, 1, 64);
    acc.y += __shfl_xor(acc.y, 1, 64);
    if (h == 0) sU[m*U_S+j] = acc;
}

// |F@W|^2 partial only (no FW store needed)
__device__ __forceinline__ float fwPartialOnly(const cf* sF, const cf* sW, int tid){
    int k = tid & 7, nb = tid >> 3;
    cf wcol[16];
    #pragma unroll
    for (int r = 0; r < 16; r++) wcol[r] = sW[r*8+k];
    float part = 0.f;
    #pragma unroll
    for (int rep = 0; rep < 2; rep++){
        int n = nb + rep*32;
        const float4* fr = (const float4*)(sF + n*F_S);
        cf acc = mkc(0,0);
        #pragma unroll
        for (int q = 0; q < 8; q++){
            float4 v = fr[q];
            cmad(acc, lo4(v), wcol[2*q]); cmad(acc, hi4(v), wcol[2*q+1]);
        }
        part += acc.x*acc.x + acc.y*acc.y;
    }
    return part;
}

// fused: |F@W|^2 partial AND Re(conj(FW)*(MF@W)) partial — FW stays in registers
__device__ __forceinline__ float2 fwTrcPartial(const cf* sF, const cf* sMF, const cf* sW, int tid){
    int k = tid & 7, nb = tid >> 3;
    cf wcol[16];
    #pragma unroll
    for (int r = 0; r < 16; r++) wcol[r] = sW[r*8+k];
    float part = 0.f, ptrc = 0.f;
    #pragma unroll
    for (int rep = 0; rep < 2; rep++){
        int n = nb + rep*32;
        const float4* fr = (const float4*)(sF + n*F_S);
        const float4* mr = (const float4*)(sMF + n*F_S);
        cf acc = mkc(0,0), acm = mkc(0,0);
        #pragma unroll
        for (int q = 0; q < 8; q++){
            float4 v = fr[q], m = mr[q];
            cmad(acc, lo4(v), wcol[2*q]); cmad(acc, hi4(v), wcol[2*q+1]);
            cmad(acm, lo4(m), wcol[2*q]); cmad(acm, hi4(m), wcol[2*q+1]);
        }
        part += acc.x*acc.x + acc.y*acc.y;
        ptrc += acc.x*acm.x + acc.y*acm.y;
    }
    return make_float2(part, ptrc);
}

// sum-rate on wave 3 (tid>=192); mul = scale^2 applied inside log; result -> *sRateVal
__device__ __forceinline__ void ratesWave3(const cf* sU, const cf* sW, float mul,
                                           float* sRateVal, int tid){
    if (tid < 192) return;
    int l = tid - 192, m = l >> 3, k = l & 7;
    cf acc = mkc(0,0);
    #pragma unroll
    for (int j = 0; j < 16; j++) cmad(acc, sU[m*U_S+j], sW[j*8+k]);
    float p = acc.x*acc.x + acc.y*acc.y;
    float tot = p;
    #pragma unroll
    for (int mask = 4; mask >= 1; mask >>= 1) tot += __shfl_xor(tot, mask, 8);
    float sig = __shfl(p, 9*m, 64);
    float rate = log2f(1.0f + (mul*sig)/fmaf(mul, tot - sig, 1.0f));
    float val = (k == 0) ? rate : 0.0f;
    #pragma unroll
    for (int mask = 32; mask >= 1; mask >>= 1) val += __shfl_xor(val, mask, 64);
    if (l == 0) *sRateVal = val;
}

// ---------------- prep: g_Mm = A_dot^H @ R_N_inv @ A_dot ----------------
__global__ __launch_bounds__(256) void pga_prep(
    const float* __restrict__ Ar, const float* __restrict__ Ai,
    const float* __restrict__ Rr, const float* __restrict__ Ri)
{
    __shared__ cf sA[4096];
    __shared__ cf Tc[512];
    int tid = threadIdx.x;
    for (int idx = tid; idx < 4096; idx += 256)
        sA[idx] = mkc(Ar[idx], Ai[idx]);
    __syncthreads();
    for (int jb = 0; jb < 8; jb++){
        int j0 = jb*8;
        #pragma unroll
        for (int rep = 0; rep < 2; rep++){
            int idx = tid + rep*256;
            int p = idx >> 3, jc = idx & 7;
            cf acc = mkc(0,0);
            for (int q = 0; q < 64; q++){
                cf rv = mkc(Rr[p*64+q], Ri[p*64+q]);
                cmad(acc, rv, sA[q*64 + j0 + jc]);
            }
            Tc[idx] = acc;
        }
        __syncthreads();
        #pragma unroll
        for (int rep = 0; rep < 2; rep++){
            int idx = tid + rep*256;
            int i = idx >> 3, jc = idx & 7;
            cf acc = mkc(0,0);
            for (int p = 0; p < 64; p++)
                cmadc(acc, sA[p*64+i], Tc[p*8+jc]);
            g_Mm[i*64 + j0 + jc] = acc;
        }
        __syncthreads();
    }
}

// ---------------- main kernel ----------------
__global__ __launch_bounds__(256, 3) void pga_main(
    const float* __restrict__ Hre, const float* __restrict__ Him,
    const float* __restrict__ F0re, const float* __restrict__ F0im,
    const float* __restrict__ W0re, const float* __restrict__ W0im,
    const float* __restrict__ xi0p,
    const int* __restrict__ Ptp, const int* __restrict__ noutp, const int* __restrict__ ninnp,
    float* __restrict__ out, int B, int cplx)
{
    const int tid = threadIdx.x;
    const int b = blockIdx.x;

    __shared__ __align__(16) char sPool[38848];
    __shared__ float sRed[12];
    __shared__ float sRateVal;

    cf* sF    = (cf*)(sPool + 0);       // 64 x 18  ( 9216 B)
    cf* sMF   = (cf*)(sPool + 9216);    // 64 x 18  ( 9216 B)
    cf* sFT   = (cf*)(sPool + 18432);   // 16 x 66  ( 8448 B)
    cf* sH    = (cf*)(sPool + 26880);   // 8 x 66   ( 4224 B)
    cf* sW    = (cf*)(sPool + 31104);   // [r*8+m]  ( 1024 B)
    cf* sV    = (cf*)(sPool + 32128);   // 16 x 18  ( 2304 B)
    cf* sU    = (cf*)(sPool + 34432);   // 8 x 18   ( 1152 B)
    cf* sRow  = (cf*)(sPool + 35584);   // [m*16+j] ( 1024 B)
    cf* sFHMF = (cf*)(sPool + 36608);   // 16 x 17  ( 2176 B)
    cf* sCoefC= (cf*)(sPool + 38784);   // [8]      (   64 B)

    const float Pt    = readScalarF(Ptp);
    const int n_outer = readScalarI(noutp);
    const int n_inner = readScalarI(ninnp);
    const float xi0   = xi0p[0];
    const int nt = n_outer * (n_inner + 1);
    const float cxi = 2.0f*xi0*xi0;

    float* outR = out;
    float* outC = out + (size_t)B * nt;
    float* outF = out + (size_t)2 * B * nt;
    float* outW = outF + (cplx ? (size_t)B * 2048 : (size_t)B * 1024);

    // ---- load H, F (projected -> sF & sFT), W ----
    cf fsf[4]; cf ssw = mkc(0.f, 0.f);
    {
        const float* hr = Hre + (size_t)b*512;
        const float* hi = Him + (size_t)b*512;
        for (int idx = tid; idx < 512; idx += 256){
            int m = idx >> 6, n = idx & 63;
            sH[m*H_S+n] = mkc(hr[idx], hi[idx]);
        }
        const float* fr = F0re + (size_t)b*1024;
        const float* fi = F0im + (size_t)b*1024;
        for (int idx = tid; idx < 1024; idx += 256){
            int n = idx >> 4, r = idx & 15;
            float re = fr[idx], im = fi[idx];
            float mag = hypotf(re, im);
            cf f = (mag > 1e-12f) ? mkc(re/mag, im/mag) : mkc(0.f, 0.f);
            sF[n*F_S+r] = f;
            sFT[r*FT_S+n] = f;
        }
        if (tid < 128)
            sW[tid] = mkc(W0re[(size_t)b*128 + tid], W0im[(size_t)b*128 + tid]);
        #pragma unroll
        for (int rep = 0; rep < 4; rep++) fsf[rep] = mkc(0.f, 0.f);
    }
    __syncthreads();

    // ---- init: u, W-normalize, MF ----
    uRefresh(sH, sFT, sU, tid);
    {
        float pw0 = blockReduceSum(fwPartialOnly(sF, sW, tid), sRed+0, tid);
        float s0 = sqrtf(Pt / pw0);
        if (tid < 128){ cf w = sW[tid]; sW[tid] = mkc(w.x*s0, w.y*s0); }
    }
    computeMF_G(sFT, sMF, tid);
    __syncthreads();

    float sp = 1.0f, sp2 = 1.0f;   // pending normalize scale of F (true F = sp * stored F)

    for (int ii = 0; ii < n_outer; ii++){
        // V = W W^H
        {
            int i = tid >> 4, jx = tid & 15;
            cf acc = mkc(0,0);
            #pragma unroll
            for (int k = 0; k < 8; k++) cmad_bc(acc, sW[i*8+k], sW[jx*8+k]);
            sV[i*V_S+jx] = acc;
        }
        __syncthreads();

        for (int jj = 0; jj < n_inner; jj++){
            const int j = tid & 15, nb = tid >> 4;

            // V row j into regs (V Hermitian: column j = conj(row j))
            cf vrow[16];
            {
                const float4* vp = (const float4*)(sV + j*V_S);
                #pragma unroll
                for (int q = 0; q < 8; q++){
                    float4 v = vp[q];
                    vrow[2*q] = lo4(v); vrow[2*q+1] = hi4(v);
                }
            }
            // G = MF@V (regs) + trace partial
            float ptr_ = 0.f;
            cf G[4];
            #pragma unroll
            for (int rep = 0; rep < 4; rep++){
                int n = nb + rep*16;
                const float4* mr = (const float4*)(sMF + n*F_S);
                cf acc = mkc(0,0);
                #pragma unroll
                for (int q = 0; q < 8; q++){
                    float4 v = mr[q];
                    cmad_bc(acc, lo4(v), vrow[2*q]); cmad_bc(acc, hi4(v), vrow[2*q+1]);
                }
                G[rep] = acc;
                cf f = sF[n*F_S+j];
                ptr_ += f.x*acc.x + f.y*acc.y;
            }
            // coef/row (tid<128), with sp-folded scaling
            if (tid < 128){
                int m = tid >> 4;
                const float4* up = (const float4*)(sU + m*U_S);
                cf t2 = mkc(0,0);
                #pragma unroll
                for (int q = 0; q < 8; q++){
                    float4 uv = up[q];
                    cmad_bc(t2, lo4(uv), vrow[2*q]); cmad_bc(t2, hi4(uv), vrow[2*q+1]);
                }
                cf u = sU[m*U_S+j];
                float qv = t2.x*u.x + t2.y*u.y;
                cf c = mkc(0,0); cmad(c, u, sW[j*8+m]);
                #pragma unroll
                for (int mask = 8; mask >= 1; mask >>= 1){
                    qv  += __shfl_xor(qv,  mask, 16);
                    c.x += __shfl_xor(c.x, mask, 16);
                    c.y += __shfl_xor(c.y, mask, 16);
                }
                float cc = c.x*c.x + c.y*c.y;
                float inv1 = 1.0f/(LN2F*(sp2*qv + 1.0f) + 1e-4f);
                float inv2 = 1.0f/(LN2F*(sp2*(qv - cc) + 1.0f) + 1e-4f);
                float a = inv1 - inv2;
                cf ci = mkc(c.x*inv2, c.y*inv2);
                cf row = mkc(t2.x*a, t2.y*a);
                cmad_bc(row, ci, sW[j*8+m]);
                sRow[tid] = row;                 // true row = sp * stored
            }
            // delayed tracking (state of previous inner iter) on wave 3
            if (jj > 0) ratesWave3(sU, sW, sp2, &sRateVal, tid);
            float tr = blockReduceSum(ptr_, sRed+0, tid);   // barrier B1
            if (jj > 0 && tid == 0){
                int t = ii*(n_inner+1) + jj;
                size_t base = (size_t)b*nt;
                outR[base + t] = sRateVal;
                outC[base + t] = 1.0f/(cxi*(sp2*tr) + 1e-12f);
            }

            // D: gF (sp-folded) + RMSProp + F update
            {
                float hinv = 0.5f/(sp*tr);
                cf rowj[8];
                #pragma unroll
                for (int m = 0; m < 8; m++){
                    cf r = sRow[m*16+j];
                    rowj[m] = mkc(sp*r.x, sp*r.y);
                }
                #pragma unroll
                for (int rep = 0; rep < 4; rep++){
                    int n = nb + rep*16;
                    cf g = mkc(G[rep].x*hinv, G[rep].y*hinv);
                    #pragma unroll
                    for (int m = 0; m < 8; m++) cmad(g, sH[m*H_S+n], rowj[m]);
                    cf sf = fsf[rep];
                    sf.x = BETA_*sf.x + OMB_*g.x;
                    sf.y = BETA_*sf.y + OMB_*g.y;
                    fsf[rep] = sf;
                    cf d = csqrtf2(sf); d.x += EPS_;
                    cf upd = cdiv(g, d);
                    cf f = sF[n*F_S+j];
                    cf fn = mkc(fmaf(ETAF_, upd.x, sp*f.x), fmaf(ETAF_, upd.y, sp*f.y));
                    sF[n*F_S+j] = fn;
                    sFT[j*FT_S+n] = fn;
                }
            }
            __syncthreads();                                 // barrier B2

            // E: MF recompute, FW/power partial, u refresh
            computeMF_G(sFT, sMF, tid);
            float part = fwPartialOnly(sF, sW, tid);
            uRefresh(sH, sFT, sU, tid);
            float pw = blockReduceSum(part, sRed+4, tid);    // barrier B3
            float s = sqrtf(Pt / pw);
            sp = s; sp2 = s*s;

            // last inner iter: explicit trace + tracking (no following G phase)
            if (jj == n_inner-1){
                float ptrl = 0.f;
                #pragma unroll
                for (int rep = 0; rep < 4; rep++){
                    int n = nb + rep*16;
                    const float4* mr = (const float4*)(sMF + n*F_S);
                    cf acc = mkc(0,0);
                    #pragma unroll
                    for (int q = 0; q < 8; q++){
                        float4 v = mr[q];
                        cmad_bc(acc, lo4(v), vrow[2*q]); cmad_bc(acc, hi4(v), vrow[2*q+1]);
                    }
                    cf f = sF[n*F_S+j];
                    ptrl += f.x*acc.x + f.y*acc.y;
                }
                ratesWave3(sU, sW, sp2, &sRateVal, tid);
                float trl = blockReduceSum(ptrl, sRed+8, tid); // barrier B4
                if (tid == 0){
                    int t = ii*(n_inner+1) + n_inner;
                    size_t base = (size_t)b*nt;
                    outR[base + t] = sRateVal;
                    outC[base + t] = 1.0f/(cxi*(sp2*trl) + 1e-12f);
                }
            }
        } // jj

        // ---- outer step ----
        const int j = tid & 15, nb = tid >> 4;
        // O1: project F (scale-invariant; threshold on true magnitude)
        {
            #pragma unroll
            for (int rep = 0; rep < 4; rep++){
                int n = nb + rep*16;
                cf f = sF[n*F_S+j];
                float mag = hypotf(f.x, f.y);
                cf fp = (sp*mag > 1e-12f) ? mkc(f.x/mag, f.y/mag) : mkc(0.f, 0.f);
                sF[n*F_S+j] = fp;
                sFT[j*FT_S+n] = fp;
            }
            sp = 1.0f; sp2 = 1.0f;
        }
        __syncthreads();
        // O2: MF = Mm@F_proj ; u = conj(H)@F_proj
        computeMF_G(sFT, sMF, tid);
        uRefresh(sH, sFT, sU, tid);
        __syncthreads();
        // O3: FHMF + tr partial ; coef via shuffles
        float ptr2;
        {
            int i = tid >> 4;
            const float4* fti = (const float4*)(sFT + i*FT_S);
            cf acc = mkc(0,0);
            #pragma unroll
            for (int q = 0; q < 32; q++){
                float4 fv = fti[q];
                cmadc(acc, lo4(fv), sMF[(2*q  )*F_S+j]);
                cmadc(acc, hi4(fv), sMF[(2*q+1)*F_S+j]);
            }
            sFHMF[i*17+j] = acc;
            cf v = sV[j*V_S+i];
            ptr2 = acc.x*v.x - acc.y*v.y;
        }
        if (tid < 128){
            int m = tid >> 4, r = tid & 15;
            cf u_mr = sU[m*U_S+r];
            const float4* up = (const float4*)(sU + m*U_S);
            cf t2 = mkc(0,0);
            #pragma unroll
            for (int q = 0; q < 8; q++){
                float4 uv = up[q];
                cmad_cc(t2, sV[(2*q)*V_S+r],   lo4(uv));
                cmad_cc(t2, sV[(2*q+1)*V_S+r], hi4(uv));
            }
            float trm = u_mr.x*t2.x - u_mr.y*t2.y;
            cf a = mkc(0,0); cmad(a, u_mr, sW[r*8+m]);
            #pragma unroll
            for (int mask = 8; mask >= 1; mask >>= 1){
                trm += __shfl_xor(trm, mask, 16);
                a.x += __shfl_xor(a.x, mask, 16);
                a.y += __shfl_xor(a.y, mask, 16);
            }
            if (r == 0){
                float invd = 1.0f/(LN2F*(trm + 1.0f)*8.0f);
                sCoefC[m] = mkc(a.x*invd, a.y*invd);
            }
        }
        float trW = blockReduceSum(ptr2, sRed+0, tid);
        // O5a: gW in regs
        cf gw = mkc(0,0);
        if (tid < 128){
            int i2 = tid >> 3, mm = tid & 7;
            cf acc = mkc(0,0);
            #pragma unroll
            for (int j2 = 0; j2 < 16; j2++) cmad(acc, sFHMF[i2*17+j2], sW[j2*8+mm]);
            float hinv = 0.5f / trW;
            gw = mkc(acc.x*hinv, acc.y*hinv);
            cmadc(gw, sU[mm*U_S+i2], sCoefC[mm]);
        }
        __syncthreads();
        // O6: RMSProp W update
        if (tid < 128){
            cf sw = ssw;
            sw.x = BETA_*sw.x + OMB_*gw.x;
            sw.y = BETA_*sw.y + OMB_*gw.y;
            ssw = sw;
            cf d = csqrtf2(sw); d.x += EPS_;
            cf upd = cdiv(gw, d);
            cf w = sW[tid];
            w.x = fmaf(ETAW_, upd.x, w.x);
            w.y = fmaf(ETAW_, upd.y, w.y);
            sW[tid] = w;
        }
        __syncthreads();
        // O7/O8: power + crb trace partials fused (FW stays in registers), one dual reduce
        float2 pq = fwTrcPartial(sF, sMF, sW, tid);
        float2 pr = blockReduceSum2(pq.x, pq.y, sRed+4, sRed+8, tid);
        float s2 = sqrtf(Pt / pr.x);
        float s2sq = s2*s2;
        // rates on pre-scale W with mul = s2^2
        ratesWave3(sU, sW, s2sq, &sRateVal, tid);
        __syncthreads();
        // O9/O10: scale W, write tracking slot ii*(n_inner+1)
        if (tid < 128){
            cf w = sW[tid];
            sW[tid] = mkc(w.x*s2, w.y*s2);
        }
        if (tid == 0){
            int t = ii*(n_inner+1);
            size_t base = (size_t)b*nt;
            outR[base + t] = sRateVal;
            outC[base + t] = 1.0f/(cxi*(s2sq*pr.y) + 1e-12f);
        }
        __syncthreads();
    } // ii

    // ---- write final F (projected, true), W (scaled) ----
    if (cplx){
        int j = tid & 15, nb = tid >> 4;
        #pragma unroll
        for (int rep = 0; rep < 4; rep++){
            int n = nb + rep*16;
            cf f = sF[n*F_S+j];
            size_t o = ((size_t)b*1024 + (size_t)(tid + rep*256))*2;
            outF[o]   = f.x;
            outF[o+1] = f.y;
        }
        if (tid < 128){
            cf w = sW[tid];
            size_t o = ((size_t)b*128 + tid)*2;
            outW[o]   = w.x;
            outW[o+1] = w.y;
        }
    } else {
        int j = tid & 15, nb = tid >> 4;
        #pragma unroll
        for (int rep = 0; rep < 4; rep++){
            int n = nb + rep*16;
            outF[(size_t)b*1024 + (size_t)(tid + rep*256)] = sF[n*F_S+j].x;
        }
        if (tid < 128)
            outW[(size_t)b*128 + tid] = sW[tid].x;
    }
}

extern "C" void kernel_launch(void* const* d_in, const int* in_sizes, int n_in,
                              void* d_out, int out_size, void* d_ws, size_t ws_size,
                              hipStream_t stream)
{
    (void)n_in; (void)d_ws; (void)ws_size;
    int B = in_sizes[0] / 512;   // A*B*Mu*N / (8*64)

    long S = (long)out_size;
    long numI = S - 2304L*B;
    long numR = S - 1152L*B;
    bool okI = (numI > 0) && (numI % (2L*B) == 0) && (numI/(2L*B) >= 1) && (numI/(2L*B) <= 256);
    bool okR = (numR > 0) && (numR % (2L*B) == 0) && (numR/(2L*B) >= 1) && (numR/(2L*B) <= 256);
    int cplx = okI ? 1 : (okR ? 0 : 1);

    pga_prep<<<1, 256, 0, stream>>>(
        (const float*)d_in[6], (const float*)d_in[7],
        (const float*)d_in[8], (const float*)d_in[9]);

    pga_main<<<B, 256, 0, stream>>>(
        (const float*)d_in[0], (const float*)d_in[1],
        (const float*)d_in[2], (const float*)d_in[3],
        (const float*)d_in[4], (const float*)d_in[5],
        (const float*)d_in[10],
        (const int*)d_in[11], (const int*)d_in[12], (const int*)d_in[13],
        (float*)d_out, B, cplx);
}

// Round 3
// 976.943 us; speedup vs baseline: 2.0301x; 2.0301x over previous
//
#include <hip/hip_runtime.h>
#include <math.h>

// ---------------- complex helpers (float2 = re,im) ----------------
typedef float2 cf;

__device__ __forceinline__ cf mkc(float x, float y){ return make_float2(x,y); }
__device__ __forceinline__ cf lo4(float4 v){ return mkc(v.x, v.y); }
__device__ __forceinline__ cf hi4(float4 v){ return mkc(v.z, v.w); }

// acc += a*b
__device__ __forceinline__ void cmad(cf& acc, cf a, cf b){
    acc.x = fmaf(a.x, b.x, fmaf(-a.y, b.y, acc.x));
    acc.y = fmaf(a.x, b.y, fmaf( a.y, b.x, acc.y));
}
// acc += conj(a)*b
__device__ __forceinline__ void cmadc(cf& acc, cf a, cf b){
    acc.x = fmaf(a.x, b.x, fmaf( a.y, b.y, acc.x));
    acc.y = fmaf(a.x, b.y, fmaf(-a.y, b.x, acc.y));
}
// acc += a*conj(b)
__device__ __forceinline__ void cmad_bc(cf& acc, cf a, cf b){
    acc.x = fmaf(a.x, b.x, fmaf( a.y, b.y, acc.x));
    acc.y = fmaf(a.y, b.x, fmaf(-a.x, b.y, acc.y));
}
// acc += conj(a)*conj(b)
__device__ __forceinline__ void cmad_cc(cf& acc, cf a, cf b){
    acc.x = fmaf(a.x, b.x, fmaf(-a.y, b.y, acc.x));
    acc.y = fmaf(-a.x, b.y, fmaf(-a.y, b.x, acc.y));
}
// principal complex sqrt (numpy branch conventions)
__device__ __forceinline__ cf csqrtf2(cf z){
    float x = z.x, y = z.y;
    float r = hypotf(x, y);
    if (r == 0.0f) return mkc(0.f, 0.f);
    if (x >= 0.0f){
        float t = sqrtf(0.5f*(r + x));
        return mkc(t, 0.5f*y/t);
    } else {
        float t = sqrtf(0.5f*(r - x));
        return mkc(0.5f*fabsf(y)/t, copysignf(t, y));
    }
}
// a / b
__device__ __forceinline__ cf cdiv(cf a, cf b){
    float inv = 1.0f/(b.x*b.x + b.y*b.y);
    return mkc((a.x*b.x + a.y*b.y)*inv, (a.y*b.x - a.x*b.y)*inv);
}

#define LN2F  0.69314718055994530942f
#define BETA_ 0.9f
#define OMB_  0.1f
#define EPS_  1e-8f
#define ETAF_ 0.01f
#define ETAW_ 0.01f

#define F_S  18   /* sF / sMF row stride (cf) */
#define FT_S 66   /* sFT row stride */
#define H_S  66   /* sH row stride */
#define U_S  18   /* sU row stride */
#define V_S  18   /* sV row stride */

// Mm = A_dot^H @ R_N_inv @ A_dot  — block-invariant, lives in global (L1/L2-resident 32KB)
__device__ cf g_Mm[4096];

__device__ __forceinline__ float readScalarF(const int* p){
    int iv = *p;
    if (iv >= 0 && iv < 1000000) return (float)iv;
    return __int_as_float(iv);
}
__device__ __forceinline__ int readScalarI(const int* p){
    int iv = *p;
    if (iv >= 0 && iv < 1000000) return iv;
    return (int)(__int_as_float(iv) + 0.5f);
}

__device__ __forceinline__ float blockReduceSum(float v, float* slot, int tid){
    #pragma unroll
    for (int o = 32; o > 0; o >>= 1) v += __shfl_down(v, o, 64);
    if ((tid & 63) == 0) slot[tid >> 6] = v;
    __syncthreads();
    return slot[0] + slot[1] + slot[2] + slot[3];
}
// two sums, one barrier
__device__ __forceinline__ float2 blockReduceSum2(float a, float b2, float* sA, float* sB, int tid){
    #pragma unroll
    for (int o = 32; o > 0; o >>= 1){ a += __shfl_down(a, o, 64); b2 += __shfl_down(b2, o, 64); }
    if ((tid & 63) == 0){ sA[tid >> 6] = a; sB[tid >> 6] = b2; }
    __syncthreads();
    return make_float2(sA[0]+sA[1]+sA[2]+sA[3], sB[0]+sB[1]+sB[2]+sB[3]);
}

// MF = Mm @ F ; Mm from GLOBAL (row stride 64 cf), F cols from sFT (row-contiguous b128).
// thread (nb=tid>>4, j=tid&15), 4 output rows. 16 lanes share each Mm address (broadcast).
// kkb loop NOT unrolled + row streams split: bounds in-flight global loads (~8 float4)
// so the 3-waves/EU register budget (≈168) is feasible without spilling.
__device__ __forceinline__ void computeMF_G(const cf* sFT, cf* sMF, int tid){
    int j = tid & 15, nb = tid >> 4;
    const float4* ftrow = (const float4*)(sFT + j*FT_S);
    cf a0=mkc(0,0), a1=mkc(0,0), a2=mkc(0,0), a3=mkc(0,0);
    #pragma unroll 1
    for (int kkb = 0; kkb < 4; kkb++){
        cf f[16];
        #pragma unroll
        for (int q = 0; q < 8; q++){
            float4 v = ftrow[kkb*8+q];
            f[2*q] = lo4(v); f[2*q+1] = hi4(v);
        }
        const float4* m0 = (const float4*)(g_Mm + (nb    )*64 + kkb*16);
        const float4* m1 = (const float4*)(g_Mm + (nb+16 )*64 + kkb*16);
        const float4* m2 = (const float4*)(g_Mm + (nb+32 )*64 + kkb*16);
        const float4* m3 = (const float4*)(g_Mm + (nb+48 )*64 + kkb*16);
        #pragma unroll
        for (int q = 0; q < 8; q++){
            float4 v0 = m0[q];
            cmad(a0, lo4(v0), f[2*q]); cmad(a0, hi4(v0), f[2*q+1]);
        }
        #pragma unroll
        for (int q = 0; q < 8; q++){
            float4 v1 = m1[q];
            cmad(a1, lo4(v1), f[2*q]); cmad(a1, hi4(v1), f[2*q+1]);
        }
        #pragma unroll
        for (int q = 0; q < 8; q++){
            float4 v2 = m2[q];
            cmad(a2, lo4(v2), f[2*q]); cmad(a2, hi4(v2), f[2*q+1]);
        }
        #pragma unroll
        for (int q = 0; q < 8; q++){
            float4 v3 = m3[q];
            cmad(a3, lo4(v3), f[2*q]); cmad(a3, hi4(v3), f[2*q+1]);
        }
    }
    sMF[(nb   )*F_S+j]=a0; sMF[(nb+16)*F_S+j]=a1;
    sMF[(nb+32)*F_S+j]=a2; sMF[(nb+48)*F_S+j]=a3;
}

// u[m][j] = sum_n conj(H[m,n]) F[n,j], split-K over 256 threads (interleaved chunks)
__device__ __forceinline__ void uRefresh(const cf* sH, const cf* sFT, cf* sU, int tid){
    int h = tid & 1, j = (tid >> 1) & 15, m = tid >> 5;
    const float4* hp = (const float4*)(sH  + m*H_S);
    const float4* fp = (const float4*)(sFT + j*FT_S);
    cf acc = mkc(0,0);
    #pragma unroll
    for (int q = 0; q < 16; q++){
        int c = 2*q + h;
        float4 hv = hp[c], fv = fp[c];
        cmadc(acc, lo4(hv), lo4(fv));
        cmadc(acc, hi4(hv), hi4(fv));
    }
    acc.x += __shfl_xor(acc.x, 1, 64);
    acc.y += __shfl_xor(acc.y, 1, 64);
    if (h == 0) sU[m*U_S+j] = acc;
}

// |F@W|^2 partial only (no FW store needed)
__device__ __forceinline__ float fwPartialOnly(const cf* sF, const cf* sW, int tid){
    int k = tid & 7, nb = tid >> 3;
    cf wcol[16];
    #pragma unroll
    for (int r = 0; r < 16; r++) wcol[r] = sW[r*8+k];
    float part = 0.f;
    #pragma unroll
    for (int rep = 0; rep < 2; rep++){
        int n = nb + rep*32;
        const float4* fr = (const float4*)(sF + n*F_S);
        cf acc = mkc(0,0);
        #pragma unroll
        for (int q = 0; q < 8; q++){
            float4 v = fr[q];
            cmad(acc, lo4(v), wcol[2*q]); cmad(acc, hi4(v), wcol[2*q+1]);
        }
        part += acc.x*acc.x + acc.y*acc.y;
    }
    return part;
}

// fused: |F@W|^2 partial AND Re(conj(FW)*(MF@W)) partial — FW stays in registers
__device__ __forceinline__ float2 fwTrcPartial(const cf* sF, const cf* sMF, const cf* sW, int tid){
    int k = tid & 7, nb = tid >> 3;
    cf wcol[16];
    #pragma unroll
    for (int r = 0; r < 16; r++) wcol[r] = sW[r*8+k];
    float part = 0.f, ptrc = 0.f;
    #pragma unroll
    for (int rep = 0; rep < 2; rep++){
        int n = nb + rep*32;
        const float4* fr = (const float4*)(sF + n*F_S);
        const float4* mr = (const float4*)(sMF + n*F_S);
        cf acc = mkc(0,0), acm = mkc(0,0);
        #pragma unroll
        for (int q = 0; q < 8; q++){
            float4 v = fr[q], m = mr[q];
            cmad(acc, lo4(v), wcol[2*q]); cmad(acc, hi4(v), wcol[2*q+1]);
            cmad(acm, lo4(m), wcol[2*q]); cmad(acm, hi4(m), wcol[2*q+1]);
        }
        part += acc.x*acc.x + acc.y*acc.y;
        ptrc += acc.x*acm.x + acc.y*acm.y;
    }
    return make_float2(part, ptrc);
}

// sum-rate on wave 3 (tid>=192); mul = scale^2 applied inside log; result -> *sRateVal
__device__ __forceinline__ void ratesWave3(const cf* sU, const cf* sW, float mul,
                                           float* sRateVal, int tid){
    if (tid < 192) return;
    int l = tid - 192, m = l >> 3, k = l & 7;
    cf acc = mkc(0,0);
    #pragma unroll
    for (int j = 0; j < 16; j++) cmad(acc, sU[m*U_S+j], sW[j*8+k]);
    float p = acc.x*acc.x + acc.y*acc.y;
    float tot = p;
    #pragma unroll
    for (int mask = 4; mask >= 1; mask >>= 1) tot += __shfl_xor(tot, mask, 8);
    float sig = __shfl(p, 9*m, 64);
    float rate = log2f(1.0f + (mul*sig)/fmaf(mul, tot - sig, 1.0f));
    float val = (k == 0) ? rate : 0.0f;
    #pragma unroll
    for (int mask = 32; mask >= 1; mask >>= 1) val += __shfl_xor(val, mask, 64);
    if (l == 0) *sRateVal = val;
}

// ---------------- prep: g_Mm = A_dot^H @ R_N_inv @ A_dot ----------------
__global__ __launch_bounds__(256) void pga_prep(
    const float* __restrict__ Ar, const float* __restrict__ Ai,
    const float* __restrict__ Rr, const float* __restrict__ Ri)
{
    __shared__ cf sA[4096];
    __shared__ cf Tc[512];
    int tid = threadIdx.x;
    for (int idx = tid; idx < 4096; idx += 256)
        sA[idx] = mkc(Ar[idx], Ai[idx]);
    __syncthreads();
    for (int jb = 0; jb < 8; jb++){
        int j0 = jb*8;
        #pragma unroll
        for (int rep = 0; rep < 2; rep++){
            int idx = tid + rep*256;
            int p = idx >> 3, jc = idx & 7;
            cf acc = mkc(0,0);
            for (int q = 0; q < 64; q++){
                cf rv = mkc(Rr[p*64+q], Ri[p*64+q]);
                cmad(acc, rv, sA[q*64 + j0 + jc]);
            }
            Tc[idx] = acc;
        }
        __syncthreads();
        #pragma unroll
        for (int rep = 0; rep < 2; rep++){
            int idx = tid + rep*256;
            int i = idx >> 3, jc = idx & 7;
            cf acc = mkc(0,0);
            for (int p = 0; p < 64; p++)
                cmadc(acc, sA[p*64+i], Tc[p*8+jc]);
            g_Mm[i*64 + j0 + jc] = acc;
        }
        __syncthreads();
    }
}

// ---------------- main kernel ----------------
// waves_per_eu(2,3): max=3 forbids the 6-wave register squeeze that caused the
// Round-2 spill catastrophe (84 VGPR, 2.25 GB scratch writes); min=2 lets the
// allocator fall back to 256 VGPRs instead of spilling if ~168 is infeasible.
__attribute__((amdgpu_waves_per_eu(2, 3)))
__global__ __launch_bounds__(256) void pga_main(
    const float* __restrict__ Hre, const float* __restrict__ Him,
    const float* __restrict__ F0re, const float* __restrict__ F0im,
    const float* __restrict__ W0re, const float* __restrict__ W0im,
    const float* __restrict__ xi0p,
    const int* __restrict__ Ptp, const int* __restrict__ noutp, const int* __restrict__ ninnp,
    float* __restrict__ out, int B, int cplx)
{
    const int tid = threadIdx.x;
    const int b = blockIdx.x;

    __shared__ __align__(16) char sPool[38848];
    __shared__ float sRed[12];
    __shared__ float sRateVal;

    cf* sF    = (cf*)(sPool + 0);       // 64 x 18  ( 9216 B)
    cf* sMF   = (cf*)(sPool + 9216);    // 64 x 18  ( 9216 B)
    cf* sFT   = (cf*)(sPool + 18432);   // 16 x 66  ( 8448 B)
    cf* sH    = (cf*)(sPool + 26880);   // 8 x 66   ( 4224 B)
    cf* sW    = (cf*)(sPool + 31104);   // [r*8+m]  ( 1024 B)
    cf* sV    = (cf*)(sPool + 32128);   // 16 x 18  ( 2304 B)
    cf* sU    = (cf*)(sPool + 34432);   // 8 x 18   ( 1152 B)
    cf* sRow  = (cf*)(sPool + 35584);   // [m*16+j] ( 1024 B)
    cf* sFHMF = (cf*)(sPool + 36608);   // 16 x 17  ( 2176 B)
    cf* sCoefC= (cf*)(sPool + 38784);   // [8]      (   64 B)

    const float Pt    = readScalarF(Ptp);
    const int n_outer = readScalarI(noutp);
    const int n_inner = readScalarI(ninnp);
    const float xi0   = xi0p[0];
    const int nt = n_outer * (n_inner + 1);
    const float cxi = 2.0f*xi0*xi0;

    float* outR = out;
    float* outC = out + (size_t)B * nt;
    float* outF = out + (size_t)2 * B * nt;
    float* outW = outF + (cplx ? (size_t)B * 2048 : (size_t)B * 1024);

    // ---- load H, F (projected -> sF & sFT), W ----
    cf fsf[4]; cf ssw = mkc(0.f, 0.f);
    {
        const float* hr = Hre + (size_t)b*512;
        const float* hi = Him + (size_t)b*512;
        for (int idx = tid; idx < 512; idx += 256){
            int m = idx >> 6, n = idx & 63;
            sH[m*H_S+n] = mkc(hr[idx], hi[idx]);
        }
        const float* fr = F0re + (size_t)b*1024;
        const float* fi = F0im + (size_t)b*1024;
        for (int idx = tid; idx < 1024; idx += 256){
            int n = idx >> 4, r = idx & 15;
            float re = fr[idx], im = fi[idx];
            float mag = hypotf(re, im);
            cf f = (mag > 1e-12f) ? mkc(re/mag, im/mag) : mkc(0.f, 0.f);
            sF[n*F_S+r] = f;
            sFT[r*FT_S+n] = f;
        }
        if (tid < 128)
            sW[tid] = mkc(W0re[(size_t)b*128 + tid], W0im[(size_t)b*128 + tid]);
        #pragma unroll
        for (int rep = 0; rep < 4; rep++) fsf[rep] = mkc(0.f, 0.f);
    }
    __syncthreads();

    // ---- init: u, W-normalize, MF ----
    uRefresh(sH, sFT, sU, tid);
    {
        float pw0 = blockReduceSum(fwPartialOnly(sF, sW, tid), sRed+0, tid);
        float s0 = sqrtf(Pt / pw0);
        if (tid < 128){ cf w = sW[tid]; sW[tid] = mkc(w.x*s0, w.y*s0); }
    }
    computeMF_G(sFT, sMF, tid);
    __syncthreads();

    float sp = 1.0f, sp2 = 1.0f;   // pending normalize scale of F (true F = sp * stored F)

    for (int ii = 0; ii < n_outer; ii++){
        // V = W W^H
        {
            int i = tid >> 4, jx = tid & 15;
            cf acc = mkc(0,0);
            #pragma unroll
            for (int k = 0; k < 8; k++) cmad_bc(acc, sW[i*8+k], sW[jx*8+k]);
            sV[i*V_S+jx] = acc;
        }
        __syncthreads();

        for (int jj = 0; jj < n_inner; jj++){
            const int j = tid & 15, nb = tid >> 4;

            // V row j into regs (V Hermitian: column j = conj(row j))
            cf vrow[16];
            {
                const float4* vp = (const float4*)(sV + j*V_S);
                #pragma unroll
                for (int q = 0; q < 8; q++){
                    float4 v = vp[q];
                    vrow[2*q] = lo4(v); vrow[2*q+1] = hi4(v);
                }
            }
            // G = MF@V (regs) + trace partial
            float ptr_ = 0.f;
            cf G[4];
            #pragma unroll
            for (int rep = 0; rep < 4; rep++){
                int n = nb + rep*16;
                const float4* mr = (const float4*)(sMF + n*F_S);
                cf acc = mkc(0,0);
                #pragma unroll
                for (int q = 0; q < 8; q++){
                    float4 v = mr[q];
                    cmad_bc(acc, lo4(v), vrow[2*q]); cmad_bc(acc, hi4(v), vrow[2*q+1]);
                }
                G[rep] = acc;
                cf f = sF[n*F_S+j];
                ptr_ += f.x*acc.x + f.y*acc.y;
            }
            // coef/row (tid<128), with sp-folded scaling
            if (tid < 128){
                int m = tid >> 4;
                const float4* up = (const float4*)(sU + m*U_S);
                cf t2 = mkc(0,0);
                #pragma unroll
                for (int q = 0; q < 8; q++){
                    float4 uv = up[q];
                    cmad_bc(t2, lo4(uv), vrow[2*q]); cmad_bc(t2, hi4(uv), vrow[2*q+1]);
                }
                cf u = sU[m*U_S+j];
                float qv = t2.x*u.x + t2.y*u.y;
                cf c = mkc(0,0); cmad(c, u, sW[j*8+m]);
                #pragma unroll
                for (int mask = 8; mask >= 1; mask >>= 1){
                    qv  += __shfl_xor(qv,  mask, 16);
                    c.x += __shfl_xor(c.x, mask, 16);
                    c.y += __shfl_xor(c.y, mask, 16);
                }
                float cc = c.x*c.x + c.y*c.y;
                float inv1 = 1.0f/(LN2F*(sp2*qv + 1.0f) + 1e-4f);
                float inv2 = 1.0f/(LN2F*(sp2*(qv - cc) + 1.0f) + 1e-4f);
                float a = inv1 - inv2;
                cf ci = mkc(c.x*inv2, c.y*inv2);
                cf row = mkc(t2.x*a, t2.y*a);
                cmad_bc(row, ci, sW[j*8+m]);
                sRow[tid] = row;                 // true row = sp * stored
            }
            // delayed tracking (state of previous inner iter) on wave 3
            if (jj > 0) ratesWave3(sU, sW, sp2, &sRateVal, tid);
            float tr = blockReduceSum(ptr_, sRed+0, tid);   // barrier B1
            if (jj > 0 && tid == 0){
                int t = ii*(n_inner+1) + jj;
                size_t base = (size_t)b*nt;
                outR[base + t] = sRateVal;
                outC[base + t] = 1.0f/(cxi*(sp2*tr) + 1e-12f);
            }

            // D: gF (sp-folded) + RMSProp + F update
            {
                float hinv = 0.5f/(sp*tr);
                cf rowj[8];
                #pragma unroll
                for (int m = 0; m < 8; m++){
                    cf r = sRow[m*16+j];
                    rowj[m] = mkc(sp*r.x, sp*r.y);
                }
                #pragma unroll
                for (int rep = 0; rep < 4; rep++){
                    int n = nb + rep*16;
                    cf g = mkc(G[rep].x*hinv, G[rep].y*hinv);
                    #pragma unroll
                    for (int m = 0; m < 8; m++) cmad(g, sH[m*H_S+n], rowj[m]);
                    cf sf = fsf[rep];
                    sf.x = BETA_*sf.x + OMB_*g.x;
                    sf.y = BETA_*sf.y + OMB_*g.y;
                    fsf[rep] = sf;
                    cf d = csqrtf2(sf); d.x += EPS_;
                    cf upd = cdiv(g, d);
                    cf f = sF[n*F_S+j];
                    cf fn = mkc(fmaf(ETAF_, upd.x, sp*f.x), fmaf(ETAF_, upd.y, sp*f.y));
                    sF[n*F_S+j] = fn;
                    sFT[j*FT_S+n] = fn;
                }
            }
            __syncthreads();                                 // barrier B2

            // E: MF recompute, FW/power partial, u refresh
            computeMF_G(sFT, sMF, tid);
            float part = fwPartialOnly(sF, sW, tid);
            uRefresh(sH, sFT, sU, tid);
            float pw = blockReduceSum(part, sRed+4, tid);    // barrier B3
            float s = sqrtf(Pt / pw);
            sp = s; sp2 = s*s;

            // last inner iter: explicit trace + tracking (no following G phase).
            // vrow REMATERIALIZED from sV here (don't keep 32 regs live across phase E).
            if (jj == n_inner-1){
                cf vrow2[16];
                {
                    const float4* vp2 = (const float4*)(sV + j*V_S);
                    #pragma unroll
                    for (int q = 0; q < 8; q++){
                        float4 v = vp2[q];
                        vrow2[2*q] = lo4(v); vrow2[2*q+1] = hi4(v);
                    }
                }
                float ptrl = 0.f;
                #pragma unroll
                for (int rep = 0; rep < 4; rep++){
                    int n = nb + rep*16;
                    const float4* mr = (const float4*)(sMF + n*F_S);
                    cf acc = mkc(0,0);
                    #pragma unroll
                    for (int q = 0; q < 8; q++){
                        float4 v = mr[q];
                        cmad_bc(acc, lo4(v), vrow2[2*q]); cmad_bc(acc, hi4(v), vrow2[2*q+1]);
                    }
                    cf f = sF[n*F_S+j];
                    ptrl += f.x*acc.x + f.y*acc.y;
                }
                ratesWave3(sU, sW, sp2, &sRateVal, tid);
                float trl = blockReduceSum(ptrl, sRed+8, tid); // barrier B4
                if (tid == 0){
                    int t = ii*(n_inner+1) + n_inner;
                    size_t base = (size_t)b*nt;
                    outR[base + t] = sRateVal;
                    outC[base + t] = 1.0f/(cxi*(sp2*trl) + 1e-12f);
                }
            }
        } // jj

        // ---- outer step ----
        const int j = tid & 15, nb = tid >> 4;
        // O1: project F (scale-invariant; threshold on true magnitude)
        {
            #pragma unroll
            for (int rep = 0; rep < 4; rep++){
                int n = nb + rep*16;
                cf f = sF[n*F_S+j];
                float mag = hypotf(f.x, f.y);
                cf fp = (sp*mag > 1e-12f) ? mkc(f.x/mag, f.y/mag) : mkc(0.f, 0.f);
                sF[n*F_S+j] = fp;
                sFT[j*FT_S+n] = fp;
            }
            sp = 1.0f; sp2 = 1.0f;
        }
        __syncthreads();
        // O2: MF = Mm@F_proj ; u = conj(H)@F_proj
        computeMF_G(sFT, sMF, tid);
        uRefresh(sH, sFT, sU, tid);
        __syncthreads();
        // O3: FHMF + tr partial ; coef via shuffles
        float ptr2;
        {
            int i = tid >> 4;
            const float4* fti = (const float4*)(sFT + i*FT_S);
            cf acc = mkc(0,0);
            #pragma unroll
            for (int q = 0; q < 32; q++){
                float4 fv = fti[q];
                cmadc(acc, lo4(fv), sMF[(2*q  )*F_S+j]);
                cmadc(acc, hi4(fv), sMF[(2*q+1)*F_S+j]);
            }
            sFHMF[i*17+j] = acc;
            cf v = sV[j*V_S+i];
            ptr2 = acc.x*v.x - acc.y*v.y;
        }
        if (tid < 128){
            int m = tid >> 4, r = tid & 15;
            cf u_mr = sU[m*U_S+r];
            const float4* up = (const float4*)(sU + m*U_S);
            cf t2 = mkc(0,0);
            #pragma unroll
            for (int q = 0; q < 8; q++){
                float4 uv = up[q];
                cmad_cc(t2, sV[(2*q)*V_S+r],   lo4(uv));
                cmad_cc(t2, sV[(2*q+1)*V_S+r], hi4(uv));
            }
            float trm = u_mr.x*t2.x - u_mr.y*t2.y;
            cf a = mkc(0,0); cmad(a, u_mr, sW[r*8+m]);
            #pragma unroll
            for (int mask = 8; mask >= 1; mask >>= 1){
                trm += __shfl_xor(trm, mask, 16);
                a.x += __shfl_xor(a.x, mask, 16);
                a.y += __shfl_xor(a.y, mask, 16);
            }
            if (r == 0){
                float invd = 1.0f/(LN2F*(trm + 1.0f)*8.0f);
                sCoefC[m] = mkc(a.x*invd, a.y*invd);
            }
        }
        float trW = blockReduceSum(ptr2, sRed+0, tid);
        // O5a: gW in regs
        cf gw = mkc(0,0);
        if (tid < 128){
            int i2 = tid >> 3, mm = tid & 7;
            cf acc = mkc(0,0);
            #pragma unroll
            for (int j2 = 0; j2 < 16; j2++) cmad(acc, sFHMF[i2*17+j2], sW[j2*8+mm]);
            float hinv = 0.5f / trW;
            gw = mkc(acc.x*hinv, acc.y*hinv);
            cmadc(gw, sU[mm*U_S+i2], sCoefC[mm]);
        }
        __syncthreads();
        // O6: RMSProp W update
        if (tid < 128){
            cf sw = ssw;
            sw.x = BETA_*sw.x + OMB_*gw.x;
            sw.y = BETA_*sw.y + OMB_*gw.y;
            ssw = sw;
            cf d = csqrtf2(sw); d.x += EPS_;
            cf upd = cdiv(gw, d);
            cf w = sW[tid];
            w.x = fmaf(ETAW_, upd.x, w.x);
            w.y = fmaf(ETAW_, upd.y, w.y);
            sW[tid] = w;
        }
        __syncthreads();
        // O7/O8: power + crb trace partials fused (FW stays in registers), one dual reduce
        float2 pq = fwTrcPartial(sF, sMF, sW, tid);
        float2 pr = blockReduceSum2(pq.x, pq.y, sRed+4, sRed+8, tid);
        float s2 = sqrtf(Pt / pr.x);
        float s2sq = s2*s2;
        // rates on pre-scale W with mul = s2^2
        ratesWave3(sU, sW, s2sq, &sRateVal, tid);
        __syncthreads();
        // O9/O10: scale W, write tracking slot ii*(n_inner+1)
        if (tid < 128){
            cf w = sW[tid];
            sW[tid] = mkc(w.x*s2, w.y*s2);
        }
        if (tid == 0){
            int t = ii*(n_inner+1);
            size_t base = (size_t)b*nt;
            outR[base + t] = sRateVal;
            outC[base + t] = 1.0f/(cxi*(s2sq*pr.y) + 1e-12f);
        }
        __syncthreads();
    } // ii

    // ---- write final F (projected, true), W (scaled) ----
    if (cplx){
        int j = tid & 15, nb = tid >> 4;
        #pragma unroll
        for (int rep = 0; rep < 4; rep++){
            int n = nb + rep*16;
            cf f = sF[n*F_S+j];
            size_t o = ((size_t)b*1024 + (size_t)(tid + rep*256))*2;
            outF[o]   = f.x;
            outF[o+1] = f.y;
        }
        if (tid < 128){
            cf w = sW[tid];
            size_t o = ((size_t)b*128 + tid)*2;
            outW[o]   = w.x;
            outW[o+1] = w.y;
        }
    } else {
        int j = tid & 15, nb = tid >> 4;
        #pragma unroll
        for (int rep = 0; rep < 4; rep++){
            int n = nb + rep*16;
            outF[(size_t)b*1024 + (size_t)(tid + rep*256)] = sF[n*F_S+j].x;
        }
        if (tid < 128)
            outW[(size_t)b*128 + tid] = sW[tid].x;
    }
}

extern "C" void kernel_launch(void* const* d_in, const int* in_sizes, int n_in,
                              void* d_out, int out_size, void* d_ws, size_t ws_size,
                              hipStream_t stream)
{
    (void)n_in; (void)d_ws; (void)ws_size;
    int B = in_sizes[0] / 512;   // A*B*Mu*N / (8*64)

    long S = (long)out_size;
    long numI = S - 2304L*B;
    long numR = S - 1152L*B;
    bool okI = (numI > 0) && (numI % (2L*B) == 0) && (numI/(2L*B) >= 1) && (numI/(2L*B) <= 256);
    bool okR = (numR > 0) && (numR % (2L*B) == 0) && (numR/(2L*B) >= 1) && (numR/(2L*B) <= 256);
    int cplx = okI ? 1 : (okR ? 0 : 1);

    pga_prep<<<1, 256, 0, stream>>>(
        (const float*)d_in[6], (const float*)d_in[7],
        (const float*)d_in[8], (const float*)d_in[9]);

    pga_main<<<B, 256, 0, stream>>>(
        (const float*)d_in[0], (const float*)d_in[1],
        (const float*)d_in[2], (const float*)d_in[3],
        (const float*)d_in[4], (const float*)d_in[5],
        (const float*)d_in[10],
        (const int*)d_in[11], (const int*)d_in[12], (const int*)d_in[13],
        (float*)d_out, B, cplx);
}

// Round 4
// 662.767 us; speedup vs baseline: 2.9924x; 1.4740x over previous
//
#include <hip/hip_runtime.h>
#include <math.h>

// ---------------- complex helpers (float2 = re,im) ----------------
typedef float2 cf;

__device__ __forceinline__ cf mkc(float x, float y){ return make_float2(x,y); }
__device__ __forceinline__ cf lo4(float4 v){ return mkc(v.x, v.y); }
__device__ __forceinline__ cf hi4(float4 v){ return mkc(v.z, v.w); }

// Complex MACs via packed-FP32 VOP3P: one v_pk_fma_f32 computes both the re and
// im halves of one a-component term. op_sel picks lo/hi 32b of each 64b source
// per result half; neg_lo/neg_hi flip product signs. Term order (a.y first,
// then a.x) matches the original fmaf nesting exactly -> bit-identical results.

// acc += a*b
//   A: lo = -(a.y*b.y)+acc.x          hi =  a.y*b.x +acc.y
//   B: lo =   a.x*b.x +lo             hi =  a.x*b.y +hi
__device__ __forceinline__ void cmad(cf& acc, cf a, cf b){
    asm("v_pk_fma_f32 %0, %1, %2, %0 op_sel:[1,1,0] op_sel_hi:[1,0,1] neg_lo:[0,1,0]\n\t"
        "v_pk_fma_f32 %0, %1, %2, %0 op_sel:[0,0,0] op_sel_hi:[0,1,1]"
        : "+v"(acc) : "v"(a), "v"(b));
}
// acc += conj(a)*b
//   A: lo =  a.y*b.y +acc.x           hi = -(a.y*b.x)+acc.y
//   B: lo =  a.x*b.x +lo              hi =  a.x*b.y +hi
__device__ __forceinline__ void cmadc(cf& acc, cf a, cf b){
    asm("v_pk_fma_f32 %0, %1, %2, %0 op_sel:[1,1,0] op_sel_hi:[1,0,1] neg_hi:[0,1,0]\n\t"
        "v_pk_fma_f32 %0, %1, %2, %0 op_sel:[0,0,0] op_sel_hi:[0,1,1]"
        : "+v"(acc) : "v"(a), "v"(b));
}
// acc += a*conj(b)
//   A: lo =  a.y*b.y +acc.x           hi = -(a.x*b.y)+acc.y
//   B: lo =  a.x*b.x +lo              hi =  a.y*b.x +hi
__device__ __forceinline__ void cmad_bc(cf& acc, cf a, cf b){
    asm("v_pk_fma_f32 %0, %1, %2, %0 op_sel:[1,1,0] op_sel_hi:[0,1,1] neg_hi:[0,1,0]\n\t"
        "v_pk_fma_f32 %0, %1, %2, %0 op_sel:[0,0,0] op_sel_hi:[1,0,1]"
        : "+v"(acc) : "v"(a), "v"(b));
}
// acc += conj(a)*conj(b)
//   A: lo = -(a.y*b.y)+acc.x          hi = -(a.y*b.x)+acc.y
//   B: lo =  a.x*b.x +lo              hi = -(a.x*b.y)+hi
__device__ __forceinline__ void cmad_cc(cf& acc, cf a, cf b){
    asm("v_pk_fma_f32 %0, %1, %2, %0 op_sel:[1,1,0] op_sel_hi:[1,0,1] neg_lo:[0,1,0] neg_hi:[0,1,0]\n\t"
        "v_pk_fma_f32 %0, %1, %2, %0 op_sel:[0,0,0] op_sel_hi:[0,1,1] neg_hi:[0,1,0]"
        : "+v"(acc) : "v"(a), "v"(b));
}
// principal complex sqrt (numpy branch conventions)
__device__ __forceinline__ cf csqrtf2(cf z){
    float x = z.x, y = z.y;
    float r = hypotf(x, y);
    if (r == 0.0f) return mkc(0.f, 0.f);
    if (x >= 0.0f){
        float t = sqrtf(0.5f*(r + x));
        return mkc(t, 0.5f*y/t);
    } else {
        float t = sqrtf(0.5f*(r - x));
        return mkc(0.5f*fabsf(y)/t, copysignf(t, y));
    }
}
// a / b
__device__ __forceinline__ cf cdiv(cf a, cf b){
    float inv = 1.0f/(b.x*b.x + b.y*b.y);
    return mkc((a.x*b.x + a.y*b.y)*inv, (a.y*b.x - a.x*b.y)*inv);
}

#define LN2F  0.69314718055994530942f
#define BETA_ 0.9f
#define OMB_  0.1f
#define EPS_  1e-8f
#define ETAF_ 0.01f
#define ETAW_ 0.01f

#define MM_S 66   /* sMm row stride (cf) */
#define F_S  18   /* sF / sMF row stride (cf) */
#define FT_S 66   /* sFT row stride */
#define H_S  66   /* sH row stride */
#define U_S  18   /* sU row stride */
#define V_S  18   /* sV row stride */

// Mm = A_dot^H @ R_N_inv @ A_dot — block-invariant, staged via global then LDS
__device__ cf g_Mm[4096];

__device__ __forceinline__ float readScalarF(const int* p){
    int iv = *p;
    if (iv >= 0 && iv < 1000000) return (float)iv;
    return __int_as_float(iv);
}
__device__ __forceinline__ int readScalarI(const int* p){
    int iv = *p;
    if (iv >= 0 && iv < 1000000) return iv;
    return (int)(__int_as_float(iv) + 0.5f);
}

__device__ __forceinline__ float blockReduceSum(float v, float* slot, int tid){
    #pragma unroll
    for (int o = 32; o > 0; o >>= 1) v += __shfl_down(v, o, 64);
    if ((tid & 63) == 0) slot[tid >> 6] = v;
    __syncthreads();
    return slot[0] + slot[1] + slot[2] + slot[3];
}
// two sums, one barrier
__device__ __forceinline__ float2 blockReduceSum2(float a, float b2, float* sA, float* sB, int tid){
    #pragma unroll
    for (int o = 32; o > 0; o >>= 1){ a += __shfl_down(a, o, 64); b2 += __shfl_down(b2, o, 64); }
    if ((tid & 63) == 0){ sA[tid >> 6] = a; sB[tid >> 6] = b2; }
    __syncthreads();
    return make_float2(sA[0]+sA[1]+sA[2]+sA[3], sB[0]+sB[1]+sB[2]+sB[3]);
}

// MF = Mm @ F via FT (row-contiguous b128). thread (nb=tid>>4, j=tid&15), 4 rows.
__device__ __forceinline__ void computeMF_T(const cf* sMm, const cf* sFT, cf* sMF, int tid){
    int j = tid & 15, nb = tid >> 4;
    cf a0=mkc(0,0), a1=mkc(0,0), a2=mkc(0,0), a3=mkc(0,0);
    const float4* ftrow = (const float4*)(sFT + j*FT_S);
    #pragma unroll
    for (int kkb = 0; kkb < 4; kkb++){
        cf f[16];
        #pragma unroll
        for (int q = 0; q < 8; q++){
            float4 v = ftrow[kkb*8+q];
            f[2*q] = lo4(v); f[2*q+1] = hi4(v);
        }
        const float4* m0 = (const float4*)(sMm + (nb    )*MM_S + kkb*16);
        const float4* m1 = (const float4*)(sMm + (nb+16 )*MM_S + kkb*16);
        const float4* m2 = (const float4*)(sMm + (nb+32 )*MM_S + kkb*16);
        const float4* m3 = (const float4*)(sMm + (nb+48 )*MM_S + kkb*16);
        #pragma unroll
        for (int q = 0; q < 8; q++){
            float4 v0 = m0[q], v1 = m1[q], v2 = m2[q], v3 = m3[q];
            cmad(a0, lo4(v0), f[2*q]); cmad(a0, hi4(v0), f[2*q+1]);
            cmad(a1, lo4(v1), f[2*q]); cmad(a1, hi4(v1), f[2*q+1]);
            cmad(a2, lo4(v2), f[2*q]); cmad(a2, hi4(v2), f[2*q+1]);
            cmad(a3, lo4(v3), f[2*q]); cmad(a3, hi4(v3), f[2*q+1]);
        }
    }
    sMF[(nb   )*F_S+j]=a0; sMF[(nb+16)*F_S+j]=a1;
    sMF[(nb+32)*F_S+j]=a2; sMF[(nb+48)*F_S+j]=a3;
}

// u[m][j] = sum_n conj(H[m,n]) F[n,j], split-K over 256 threads (interleaved chunks)
__device__ __forceinline__ void uRefresh(const cf* sH, const cf* sFT, cf* sU, int tid){
    int h = tid & 1, j = (tid >> 1) & 15, m = tid >> 5;
    const float4* hp = (const float4*)(sH  + m*H_S);
    const float4* fp = (const float4*)(sFT + j*FT_S);
    cf acc = mkc(0,0);
    #pragma unroll
    for (int q = 0; q < 16; q++){
        int c = 2*q + h;
        float4 hv = hp[c], fv = fp[c];
        cmadc(acc, lo4(hv), lo4(fv));
        cmadc(acc, hi4(hv), hi4(fv));
    }
    acc.x += __shfl_xor(acc.x, 1, 64);
    acc.y += __shfl_xor(acc.y, 1, 64);
    if (h == 0) sU[m*U_S+j] = acc;
}

// |F@W|^2 partial only (no FW store needed)
__device__ __forceinline__ float fwPartialOnly(const cf* sF, const cf* sW, int tid){
    int k = tid & 7, nb = tid >> 3;
    cf wcol[16];
    #pragma unroll
    for (int r = 0; r < 16; r++) wcol[r] = sW[r*8+k];
    float part = 0.f;
    #pragma unroll
    for (int rep = 0; rep < 2; rep++){
        int n = nb + rep*32;
        const float4* fr = (const float4*)(sF + n*F_S);
        cf acc = mkc(0,0);
        #pragma unroll
        for (int q = 0; q < 8; q++){
            float4 v = fr[q];
            cmad(acc, lo4(v), wcol[2*q]); cmad(acc, hi4(v), wcol[2*q+1]);
        }
        part += acc.x*acc.x + acc.y*acc.y;
    }
    return part;
}

// fused: |F@W|^2 partial AND Re(conj(FW)*(MF@W)) partial — FW stays in registers
__device__ __forceinline__ float2 fwTrcPartial(const cf* sF, const cf* sMF, const cf* sW, int tid){
    int k = tid & 7, nb = tid >> 3;
    cf wcol[16];
    #pragma unroll
    for (int r = 0; r < 16; r++) wcol[r] = sW[r*8+k];
    float part = 0.f, ptrc = 0.f;
    #pragma unroll
    for (int rep = 0; rep < 2; rep++){
        int n = nb + rep*32;
        const float4* fr = (const float4*)(sF + n*F_S);
        const float4* mr = (const float4*)(sMF + n*F_S);
        cf acc = mkc(0,0), acm = mkc(0,0);
        #pragma unroll
        for (int q = 0; q < 8; q++){
            float4 v = fr[q], m = mr[q];
            cmad(acc, lo4(v), wcol[2*q]); cmad(acc, hi4(v), wcol[2*q+1]);
            cmad(acm, lo4(m), wcol[2*q]); cmad(acm, hi4(m), wcol[2*q+1]);
        }
        part += acc.x*acc.x + acc.y*acc.y;
        ptrc += acc.x*acm.x + acc.y*acm.y;
    }
    return make_float2(part, ptrc);
}

// sum-rate on wave 3 (tid>=192); mul = scale^2 applied inside log; result -> *sRateVal
__device__ __forceinline__ void ratesWave3(const cf* sU, const cf* sW, float mul,
                                           float* sRateVal, int tid){
    if (tid < 192) return;
    int l = tid - 192, m = l >> 3, k = l & 7;
    cf acc = mkc(0,0);
    #pragma unroll
    for (int j = 0; j < 16; j++) cmad(acc, sU[m*U_S+j], sW[j*8+k]);
    float p = acc.x*acc.x + acc.y*acc.y;
    float tot = p;
    #pragma unroll
    for (int mask = 4; mask >= 1; mask >>= 1) tot += __shfl_xor(tot, mask, 8);
    float sig = __shfl(p, 9*m, 64);
    float rate = log2f(1.0f + (mul*sig)/fmaf(mul, tot - sig, 1.0f));
    float val = (k == 0) ? rate : 0.0f;
    #pragma unroll
    for (int mask = 32; mask >= 1; mask >>= 1) val += __shfl_xor(val, mask, 64);
    if (l == 0) *sRateVal = val;
}

// ---------------- prep: g_Mm = A_dot^H @ R_N_inv @ A_dot ----------------
__global__ __launch_bounds__(256) void pga_prep(
    const float* __restrict__ Ar, const float* __restrict__ Ai,
    const float* __restrict__ Rr, const float* __restrict__ Ri)
{
    __shared__ cf sA[4096];
    __shared__ cf Tc[512];
    int tid = threadIdx.x;
    for (int idx = tid; idx < 4096; idx += 256)
        sA[idx] = mkc(Ar[idx], Ai[idx]);
    __syncthreads();
    for (int jb = 0; jb < 8; jb++){
        int j0 = jb*8;
        #pragma unroll
        for (int rep = 0; rep < 2; rep++){
            int idx = tid + rep*256;
            int p = idx >> 3, jc = idx & 7;
            cf acc = mkc(0,0);
            for (int q = 0; q < 64; q++){
                cf rv = mkc(Rr[p*64+q], Ri[p*64+q]);
                cmad(acc, rv, sA[q*64 + j0 + jc]);
            }
            Tc[idx] = acc;
        }
        __syncthreads();
        #pragma unroll
        for (int rep = 0; rep < 2; rep++){
            int idx = tid + rep*256;
            int i = idx >> 3, jc = idx & 7;
            cf acc = mkc(0,0);
            for (int p = 0; p < 64; p++)
                cmadc(acc, sA[p*64+i], Tc[p*8+jc]);
            g_Mm[i*64 + j0 + jc] = acc;
        }
        __syncthreads();
    }
}

// ---------------- main kernel ----------------
// No waves_per_eu / min-occupancy attribute: Round-3 proved occupancy-insensitivity
// (2 vs 4 blocks/CU -> same dur, same VALUBusy); the natural 256-VGPR allocation is
// the proven no-spill regime (Round-2/3 spills cost 2x / WRITE_SIZE 65 MB).
__global__ __launch_bounds__(256) void pga_main(
    const float* __restrict__ Hre, const float* __restrict__ Him,
    const float* __restrict__ F0re, const float* __restrict__ F0im,
    const float* __restrict__ W0re, const float* __restrict__ W0im,
    const float* __restrict__ xi0p,
    const int* __restrict__ Ptp, const int* __restrict__ noutp, const int* __restrict__ ninnp,
    float* __restrict__ out, int B, int cplx)
{
    const int tid = threadIdx.x;
    const int b = blockIdx.x;

    __shared__ __align__(16) char sPool[72640];
    __shared__ float sRed[12];
    __shared__ float sRateVal;

    cf* sMm   = (cf*)(sPool + 0);       // 64 x 66  (33792 B)
    cf* sF    = (cf*)(sPool + 33792);   // 64 x 18  ( 9216 B)
    cf* sMF   = (cf*)(sPool + 43008);   // 64 x 18  ( 9216 B)
    cf* sFT   = (cf*)(sPool + 52224);   // 16 x 66  ( 8448 B)
    cf* sH    = (cf*)(sPool + 60672);   // 8 x 66   ( 4224 B)
    cf* sW    = (cf*)(sPool + 64896);   // [r*8+m]  ( 1024 B)
    cf* sV    = (cf*)(sPool + 65920);   // 16 x 18  ( 2304 B)
    cf* sU    = (cf*)(sPool + 68224);   // 8 x 18   ( 1152 B)
    cf* sRow  = (cf*)(sPool + 69376);   // [m*16+j] ( 1024 B)
    cf* sFHMF = (cf*)(sPool + 70400);   // 16 x 17  ( 2176 B)
    cf* sCoefC= (cf*)(sPool + 72576);   // [8]      (   64 B)

    const float Pt    = readScalarF(Ptp);
    const int n_outer = readScalarI(noutp);
    const int n_inner = readScalarI(ninnp);
    const float xi0   = xi0p[0];
    const int nt = n_outer * (n_inner + 1);
    const float cxi = 2.0f*xi0*xi0;

    float* outR = out;
    float* outC = out + (size_t)B * nt;
    float* outF = out + (size_t)2 * B * nt;
    float* outW = outF + (cplx ? (size_t)B * 2048 : (size_t)B * 1024);

    // ---- load Mm (global -> LDS), H, F (projected -> sF & sFT), W ----
    cf fsf[4]; cf ssw = mkc(0.f, 0.f);
    {
        for (int idx = tid; idx < 4096; idx += 256){
            int r = idx >> 6, c = idx & 63;
            sMm[r*MM_S+c] = g_Mm[idx];
        }
        const float* hr = Hre + (size_t)b*512;
        const float* hi = Him + (size_t)b*512;
        for (int idx = tid; idx < 512; idx += 256){
            int m = idx >> 6, n = idx & 63;
            sH[m*H_S+n] = mkc(hr[idx], hi[idx]);
        }
        const float* fr = F0re + (size_t)b*1024;
        const float* fi = F0im + (size_t)b*1024;
        for (int idx = tid; idx < 1024; idx += 256){
            int n = idx >> 4, r = idx & 15;
            float re = fr[idx], im = fi[idx];
            float mag = hypotf(re, im);
            cf f = (mag > 1e-12f) ? mkc(re/mag, im/mag) : mkc(0.f, 0.f);
            sF[n*F_S+r] = f;
            sFT[r*FT_S+n] = f;
        }
        if (tid < 128)
            sW[tid] = mkc(W0re[(size_t)b*128 + tid], W0im[(size_t)b*128 + tid]);
        #pragma unroll
        for (int rep = 0; rep < 4; rep++) fsf[rep] = mkc(0.f, 0.f);
    }
    __syncthreads();

    // ---- init: u, W-normalize, MF ----
    uRefresh(sH, sFT, sU, tid);
    {
        float pw0 = blockReduceSum(fwPartialOnly(sF, sW, tid), sRed+0, tid);
        float s0 = sqrtf(Pt / pw0);
        if (tid < 128){ cf w = sW[tid]; sW[tid] = mkc(w.x*s0, w.y*s0); }
    }
    computeMF_T(sMm, sFT, sMF, tid);
    __syncthreads();

    float sp = 1.0f, sp2 = 1.0f;   // pending normalize scale of F (true F = sp * stored F)

    for (int ii = 0; ii < n_outer; ii++){
        // V = W W^H
        {
            int i = tid >> 4, jx = tid & 15;
            cf acc = mkc(0,0);
            #pragma unroll
            for (int k = 0; k < 8; k++) cmad_bc(acc, sW[i*8+k], sW[jx*8+k]);
            sV[i*V_S+jx] = acc;
        }
        __syncthreads();

        for (int jj = 0; jj < n_inner; jj++){
            const int j = tid & 15, nb = tid >> 4;

            // V row j into regs (V Hermitian: column j = conj(row j))
            cf vrow[16];
            {
                const float4* vp = (const float4*)(sV + j*V_S);
                #pragma unroll
                for (int q = 0; q < 8; q++){
                    float4 v = vp[q];
                    vrow[2*q] = lo4(v); vrow[2*q+1] = hi4(v);
                }
            }
            // G = MF@V (regs) + trace partial
            float ptr_ = 0.f;
            cf G[4];
            #pragma unroll
            for (int rep = 0; rep < 4; rep++){
                int n = nb + rep*16;
                const float4* mr = (const float4*)(sMF + n*F_S);
                cf acc = mkc(0,0);
                #pragma unroll
                for (int q = 0; q < 8; q++){
                    float4 v = mr[q];
                    cmad_bc(acc, lo4(v), vrow[2*q]); cmad_bc(acc, hi4(v), vrow[2*q+1]);
                }
                G[rep] = acc;
                cf f = sF[n*F_S+j];
                ptr_ += f.x*acc.x + f.y*acc.y;
            }
            // coef/row (tid<128), with sp-folded scaling
            if (tid < 128){
                int m = tid >> 4;
                const float4* up = (const float4*)(sU + m*U_S);
                cf t2 = mkc(0,0);
                #pragma unroll
                for (int q = 0; q < 8; q++){
                    float4 uv = up[q];
                    cmad_bc(t2, lo4(uv), vrow[2*q]); cmad_bc(t2, hi4(uv), vrow[2*q+1]);
                }
                cf u = sU[m*U_S+j];
                float qv = t2.x*u.x + t2.y*u.y;
                cf c = mkc(0,0); cmad(c, u, sW[j*8+m]);
                #pragma unroll
                for (int mask = 8; mask >= 1; mask >>= 1){
                    qv  += __shfl_xor(qv,  mask, 16);
                    c.x += __shfl_xor(c.x, mask, 16);
                    c.y += __shfl_xor(c.y, mask, 16);
                }
                float cc = c.x*c.x + c.y*c.y;
                float inv1 = 1.0f/(LN2F*(sp2*qv + 1.0f) + 1e-4f);
                float inv2 = 1.0f/(LN2F*(sp2*(qv - cc) + 1.0f) + 1e-4f);
                float a = inv1 - inv2;
                cf ci = mkc(c.x*inv2, c.y*inv2);
                cf row = mkc(t2.x*a, t2.y*a);
                cmad_bc(row, ci, sW[j*8+m]);
                sRow[tid] = row;                 // true row = sp * stored
            }
            // delayed tracking (state of previous inner iter) on wave 3
            if (jj > 0) ratesWave3(sU, sW, sp2, &sRateVal, tid);
            float tr = blockReduceSum(ptr_, sRed+0, tid);   // barrier B1
            if (jj > 0 && tid == 0){
                int t = ii*(n_inner+1) + jj;
                size_t base = (size_t)b*nt;
                outR[base + t] = sRateVal;
                outC[base + t] = 1.0f/(cxi*(sp2*tr) + 1e-12f);
            }

            // D: gF (sp-folded) + RMSProp + F update
            {
                float hinv = 0.5f/(sp*tr);
                cf rowj[8];
                #pragma unroll
                for (int m = 0; m < 8; m++){
                    cf r = sRow[m*16+j];
                    rowj[m] = mkc(sp*r.x, sp*r.y);
                }
                #pragma unroll
                for (int rep = 0; rep < 4; rep++){
                    int n = nb + rep*16;
                    cf g = mkc(G[rep].x*hinv, G[rep].y*hinv);
                    #pragma unroll
                    for (int m = 0; m < 8; m++) cmad(g, sH[m*H_S+n], rowj[m]);
                    cf sf = fsf[rep];
                    sf.x = BETA_*sf.x + OMB_*g.x;
                    sf.y = BETA_*sf.y + OMB_*g.y;
                    fsf[rep] = sf;
                    cf d = csqrtf2(sf); d.x += EPS_;
                    cf upd = cdiv(g, d);
                    cf f = sF[n*F_S+j];
                    cf fn = mkc(fmaf(ETAF_, upd.x, sp*f.x), fmaf(ETAF_, upd.y, sp*f.y));
                    sF[n*F_S+j] = fn;
                    sFT[j*FT_S+n] = fn;
                }
            }
            __syncthreads();                                 // barrier B2

            // E: MF recompute, FW/power partial, u refresh
            computeMF_T(sMm, sFT, sMF, tid);
            float part = fwPartialOnly(sF, sW, tid);
            uRefresh(sH, sFT, sU, tid);
            float pw = blockReduceSum(part, sRed+4, tid);    // barrier B3
            float s = sqrtf(Pt / pw);
            sp = s; sp2 = s*s;

            // last inner iter: explicit trace + tracking (no following G phase).
            // vrow rematerialized from sV (don't keep 32 regs live across phase E).
            if (jj == n_inner-1){
                cf vrow2[16];
                {
                    const float4* vp2 = (const float4*)(sV + j*V_S);
                    #pragma unroll
                    for (int q = 0; q < 8; q++){
                        float4 v = vp2[q];
                        vrow2[2*q] = lo4(v); vrow2[2*q+1] = hi4(v);
                    }
                }
                float ptrl = 0.f;
                #pragma unroll
                for (int rep = 0; rep < 4; rep++){
                    int n = nb + rep*16;
                    const float4* mr = (const float4*)(sMF + n*F_S);
                    cf acc = mkc(0,0);
                    #pragma unroll
                    for (int q = 0; q < 8; q++){
                        float4 v = mr[q];
                        cmad_bc(acc, lo4(v), vrow2[2*q]); cmad_bc(acc, hi4(v), vrow2[2*q+1]);
                    }
                    cf f = sF[n*F_S+j];
                    ptrl += f.x*acc.x + f.y*acc.y;
                }
                ratesWave3(sU, sW, sp2, &sRateVal, tid);
                float trl = blockReduceSum(ptrl, sRed+8, tid); // barrier B4
                if (tid == 0){
                    int t = ii*(n_inner+1) + n_inner;
                    size_t base = (size_t)b*nt;
                    outR[base + t] = sRateVal;
                    outC[base + t] = 1.0f/(cxi*(sp2*trl) + 1e-12f);
                }
            }
        } // jj

        // ---- outer step ----
        const int j = tid & 15, nb = tid >> 4;
        // O1: project F (scale-invariant; threshold on true magnitude)
        {
            #pragma unroll
            for (int rep = 0; rep < 4; rep++){
                int n = nb + rep*16;
                cf f = sF[n*F_S+j];
                float mag = hypotf(f.x, f.y);
                cf fp = (sp*mag > 1e-12f) ? mkc(f.x/mag, f.y/mag) : mkc(0.f, 0.f);
                sF[n*F_S+j] = fp;
                sFT[j*FT_S+n] = fp;
            }
            sp = 1.0f; sp2 = 1.0f;
        }
        __syncthreads();
        // O2: MF = Mm@F_proj ; u = conj(H)@F_proj
        computeMF_T(sMm, sFT, sMF, tid);
        uRefresh(sH, sFT, sU, tid);
        __syncthreads();
        // O3: FHMF + tr partial ; coef via shuffles
        float ptr2;
        {
            int i = tid >> 4;
            const float4* fti = (const float4*)(sFT + i*FT_S);
            cf acc = mkc(0,0);
            #pragma unroll
            for (int q = 0; q < 32; q++){
                float4 fv = fti[q];
                cmadc(acc, lo4(fv), sMF[(2*q  )*F_S+j]);
                cmadc(acc, hi4(fv), sMF[(2*q+1)*F_S+j]);
            }
            sFHMF[i*17+j] = acc;
            cf v = sV[j*V_S+i];
            ptr2 = acc.x*v.x - acc.y*v.y;
        }
        if (tid < 128){
            int m = tid >> 4, r = tid & 15;
            cf u_mr = sU[m*U_S+r];
            const float4* up = (const float4*)(sU + m*U_S);
            cf t2 = mkc(0,0);
            #pragma unroll
            for (int q = 0; q < 8; q++){
                float4 uv = up[q];
                cmad_cc(t2, sV[(2*q)*V_S+r],   lo4(uv));
                cmad_cc(t2, sV[(2*q+1)*V_S+r], hi4(uv));
            }
            float trm = u_mr.x*t2.x - u_mr.y*t2.y;
            cf a = mkc(0,0); cmad(a, u_mr, sW[r*8+m]);
            #pragma unroll
            for (int mask = 8; mask >= 1; mask >>= 1){
                trm += __shfl_xor(trm, mask, 16);
                a.x += __shfl_xor(a.x, mask, 16);
                a.y += __shfl_xor(a.y, mask, 16);
            }
            if (r == 0){
                float invd = 1.0f/(LN2F*(trm + 1.0f)*8.0f);
                sCoefC[m] = mkc(a.x*invd, a.y*invd);
            }
        }
        float trW = blockReduceSum(ptr2, sRed+0, tid);
        // O5a: gW in regs
        cf gw = mkc(0,0);
        if (tid < 128){
            int i2 = tid >> 3, mm = tid & 7;
            cf acc = mkc(0,0);
            #pragma unroll
            for (int j2 = 0; j2 < 16; j2++) cmad(acc, sFHMF[i2*17+j2], sW[j2*8+mm]);
            float hinv = 0.5f / trW;
            gw = mkc(acc.x*hinv, acc.y*hinv);
            cmadc(gw, sU[mm*U_S+i2], sCoefC[mm]);
        }
        __syncthreads();
        // O6: RMSProp W update
        if (tid < 128){
            cf sw = ssw;
            sw.x = BETA_*sw.x + OMB_*gw.x;
            sw.y = BETA_*sw.y + OMB_*gw.y;
            ssw = sw;
            cf d = csqrtf2(sw); d.x += EPS_;
            cf upd = cdiv(gw, d);
            cf w = sW[tid];
            w.x = fmaf(ETAW_, upd.x, w.x);
            w.y = fmaf(ETAW_, upd.y, w.y);
            sW[tid] = w;
        }
        __syncthreads();
        // O7/O8: power + crb trace partials fused (FW stays in registers), one dual reduce
        float2 pq = fwTrcPartial(sF, sMF, sW, tid);
        float2 pr = blockReduceSum2(pq.x, pq.y, sRed+4, sRed+8, tid);
        float s2 = sqrtf(Pt / pr.x);
        float s2sq = s2*s2;
        // rates on pre-scale W with mul = s2^2
        ratesWave3(sU, sW, s2sq, &sRateVal, tid);
        __syncthreads();
        // O9/O10: scale W, write tracking slot ii*(n_inner+1)
        if (tid < 128){
            cf w = sW[tid];
            sW[tid] = mkc(w.x*s2, w.y*s2);
        }
        if (tid == 0){
            int t = ii*(n_inner+1);
            size_t base = (size_t)b*nt;
            outR[base + t] = sRateVal;
            outC[base + t] = 1.0f/(cxi*(s2sq*pr.y) + 1e-12f);
        }
        __syncthreads();
    } // ii

    // ---- write final F (projected, true), W (scaled) ----
    if (cplx){
        int j = tid & 15, nb = tid >> 4;
        #pragma unroll
        for (int rep = 0; rep < 4; rep++){
            int n = nb + rep*16;
            cf f = sF[n*F_S+j];
            size_t o = ((size_t)b*1024 + (size_t)(tid + rep*256))*2;
            outF[o]   = f.x;
            outF[o+1] = f.y;
        }
        if (tid < 128){
            cf w = sW[tid];
            size_t o = ((size_t)b*128 + tid)*2;
            outW[o]   = w.x;
            outW[o+1] = w.y;
        }
    } else {
        int j = tid & 15, nb = tid >> 4;
        #pragma unroll
        for (int rep = 0; rep < 4; rep++){
            int n = nb + rep*16;
            outF[(size_t)b*1024 + (size_t)(tid + rep*256)] = sF[n*F_S+j].x;
        }
        if (tid < 128)
            outW[(size_t)b*128 + tid] = sW[tid].x;
    }
}

extern "C" void kernel_launch(void* const* d_in, const int* in_sizes, int n_in,
                              void* d_out, int out_size, void* d_ws, size_t ws_size,
                              hipStream_t stream)
{
    (void)n_in; (void)d_ws; (void)ws_size;
    int B = in_sizes[0] / 512;   // A*B*Mu*N / (8*64)

    long S = (long)out_size;
    long numI = S - 2304L*B;
    long numR = S - 1152L*B;
    bool okI = (numI > 0) && (numI % (2L*B) == 0) && (numI/(2L*B) >= 1) && (numI/(2L*B) <= 256);
    bool okR = (numR > 0) && (numR % (2L*B) == 0) && (numR/(2L*B) >= 1) && (numR/(2L*B) <= 256);
    int cplx = okI ? 1 : (okR ? 0 : 1);

    pga_prep<<<1, 256, 0, stream>>>(
        (const float*)d_in[6], (const float*)d_in[7],
        (const float*)d_in[8], (const float*)d_in[9]);

    pga_main<<<B, 256, 0, stream>>>(
        (const float*)d_in[0], (const float*)d_in[1],
        (const float*)d_in[2], (const float*)d_in[3],
        (const float*)d_in[4], (const float*)d_in[5],
        (const float*)d_in[10],
        (const int*)d_in[11], (const int*)d_in[12], (const int*)d_in[13],
        (float*)d_out, B, cplx);
}